// Round 2
// baseline (28982.413 us; speedup 1.0000x reference)
//
#include <hip/hip_runtime.h>
#include <hip/hip_bf16.h>

#define NB 64
#define TT 1024
#define ND 512
#define NH 1024
#define GRID 256
#define NTH 256

typedef float f32x4 __attribute__((ext_vector_type(4)));
typedef __bf16 bf16x8 __attribute__((ext_vector_type(8)));

__device__ __forceinline__ float sigmoid_f(float v) { return 1.0f / (1.0f + __expf(-v)); }

__device__ __forceinline__ float tanh_f(float v) {
    float a = fabsf(v);
    float e = __expf(-2.0f * a);
    float t = (1.0f - e) / (1.0f + e);
    return copysignf(t, v);
}

// LDS weights are stored in exact MFMA B-fragment order so every read is a
// lane-contiguous ds_read_b128 (conflict-free):
//   WihF[((w*4+it)*3+g)*64 + lane][8]  : k = w*128+it*32+(lane>>4)*8+j, col = g*16+(lane&15)
//   WhhF[((w*8+it)*3+g)*64 + lane][8]  : k = w*256+it*32+(lane>>4)*8+j
__global__ void __launch_bounds__(NTH) gru_kernel(
    const float* __restrict__ x, const float* __restrict__ W_ih,
    const float* __restrict__ W_hh, const float* __restrict__ b_ih,
    const float* __restrict__ b_hh, float* __restrict__ out,
    unsigned* __restrict__ flags, __bf16* __restrict__ hbuf)
{
    extern __shared__ char smem[];
    __bf16* WihF = (__bf16*)smem;                  // 4*4*3*64*8 bf16 = 49152 B
    __bf16* WhhF = WihF + 4 * 4 * 3 * 64 * 8;      // 4*8*3*64*8 bf16 = 98304 B
    float* prz = (float*)(WhhF + 4 * 8 * 3 * 64 * 8);  // [4][16][32] = 8192 B
    float* pnx = prz + 2048;                       // [4][16][16] = 4096 B
    float* pnh = pnx + 1024;                       // [4][16][16] = 4096 B
    // total 163840 B

    const int tid = threadIdx.x;
    const int bg = blockIdx.x >> 6;   // batch group (16 rows) — independent sync group
    const int cg = blockIdx.x & 63;   // hidden-col group (16 cols)
    const int brow = bg << 4;
    const int hc0 = cg << 4;

    // ---- one-time: fill fragment-ordered weight LDS (fp32 -> bf16) ----
    for (int s = tid; s < 4 * 4 * 3 * 64; s += NTH) {      // W_ih slots
        int lane = s & 63, r = s >> 6;
        int g = r % 3, r2 = r / 3;
        int it = r2 & 3, w = r2 >> 2;
        int k = w * 128 + it * 32 + (lane >> 4) * 8;
        int col = lane & 15;
        const float* src = W_ih + (size_t)(g * NH + hc0 + col) * ND + k;
        float4 va = *(const float4*)(src);
        float4 vb = *(const float4*)(src + 4);
        bf16x8 f;
        f[0] = (__bf16)va.x; f[1] = (__bf16)va.y; f[2] = (__bf16)va.z; f[3] = (__bf16)va.w;
        f[4] = (__bf16)vb.x; f[5] = (__bf16)vb.y; f[6] = (__bf16)vb.z; f[7] = (__bf16)vb.w;
        *(bf16x8*)(WihF + (size_t)s * 8) = f;
    }
    for (int s = tid; s < 4 * 8 * 3 * 64; s += NTH) {      // W_hh slots
        int lane = s & 63, r = s >> 6;
        int g = r % 3, r2 = r / 3;
        int it = r2 & 7, w = r2 >> 3;
        int k = w * 256 + it * 32 + (lane >> 4) * 8;
        int col = lane & 15;
        const float* src = W_hh + (size_t)(g * NH + hc0 + col) * NH + k;
        float4 va = *(const float4*)(src);
        float4 vb = *(const float4*)(src + 4);
        bf16x8 f;
        f[0] = (__bf16)va.x; f[1] = (__bf16)va.y; f[2] = (__bf16)va.z; f[3] = (__bf16)va.w;
        f[4] = (__bf16)vb.x; f[5] = (__bf16)vb.y; f[6] = (__bf16)vb.z; f[7] = (__bf16)vb.w;
        *(bf16x8*)(WhhF + (size_t)s * 8) = f;
    }

    const int jcol = tid & 15;
    const int mrow = tid >> 4;
    const float b_r = b_ih[hc0 + jcol] + b_hh[hc0 + jcol];
    const float b_z = b_ih[NH + hc0 + jcol] + b_hh[NH + hc0 + jcol];
    const float b_nx = b_ih[2 * NH + hc0 + jcol];
    const float b_nh = b_hh[2 * NH + hc0 + jcol];

    __syncthreads();

    const int wave = tid >> 6;
    const int lane = tid & 63;
    const int lrow = lane & 15;
    const int kgrp = lane >> 4;

    unsigned* myflag = flags + ((size_t)(bg * 64 + cg)) * 16;        // own 64B line
    unsigned* pollflag = flags + ((size_t)(bg * 64 + (tid & 63))) * 16;  // wave0 gather

    float hp = 0.0f;   // fp32 hidden-state carry lives in a register
    int p = 0;
    for (int t = 0; t < TT; ++t) {
        f32x4 ar{}, az{}, anx{}, anh{};

        // ---- x-part (independent of h — runs while peer flags propagate) ----
        const float* xrow = x + ((size_t)(brow + lrow) * TT + t) * ND + wave * 128 + kgrp * 8;
        #pragma unroll
        for (int it = 0; it < 4; ++it) {
            float4 va = *(const float4*)(xrow + it * 32);
            float4 vb = *(const float4*)(xrow + it * 32 + 4);
            bf16x8 af;
            af[0] = (__bf16)va.x; af[1] = (__bf16)va.y; af[2] = (__bf16)va.z; af[3] = (__bf16)va.w;
            af[4] = (__bf16)vb.x; af[5] = (__bf16)vb.y; af[6] = (__bf16)vb.z; af[7] = (__bf16)vb.w;
            const __bf16* wp = WihF + ((size_t)(wave * 4 + it) * 3) * 512 + lane * 8;
            bf16x8 wr = *(const bf16x8*)(wp);
            bf16x8 wz = *(const bf16x8*)(wp + 512);
            bf16x8 wn = *(const bf16x8*)(wp + 1024);
            ar  = __builtin_amdgcn_mfma_f32_16x16x32_bf16(af, wr, ar, 0, 0, 0);
            az  = __builtin_amdgcn_mfma_f32_16x16x32_bf16(af, wz, az, 0, 0, 0);
            anx = __builtin_amdgcn_mfma_f32_16x16x32_bf16(af, wn, anx, 0, 0, 0);
        }

        // ---- wait for peer h writes (all-observe flag barrier, no atom RMW) ----
        if (t > 0) {
            if (tid < 64) {
                const unsigned tgt = (unsigned)t;
                for (;;) {
                    unsigned v = __hip_atomic_load(pollflag, __ATOMIC_RELAXED,
                                                   __HIP_MEMORY_SCOPE_AGENT);
                    if (__all(v >= tgt)) break;
                    __builtin_amdgcn_s_sleep(1);
                }
                __threadfence();   // acquire: invalidate stale L1/L2 (cache-wide op)
            }
            __syncthreads();
        }

        // ---- h-part ----
        const __bf16* hrow = hbuf + (size_t)p * NB * NH + (size_t)(brow + lrow) * NH
                           + wave * 256 + kgrp * 8;
        #pragma unroll
        for (int it = 0; it < 8; ++it) {
            bf16x8 af = *(const bf16x8*)(hrow + it * 32);
            const __bf16* wp = WhhF + ((size_t)(wave * 8 + it) * 3) * 512 + lane * 8;
            bf16x8 wr = *(const bf16x8*)(wp);
            bf16x8 wz = *(const bf16x8*)(wp + 512);
            bf16x8 wn = *(const bf16x8*)(wp + 1024);
            ar  = __builtin_amdgcn_mfma_f32_16x16x32_bf16(af, wr, ar, 0, 0, 0);
            az  = __builtin_amdgcn_mfma_f32_16x16x32_bf16(af, wz, az, 0, 0, 0);
            anh = __builtin_amdgcn_mfma_f32_16x16x32_bf16(af, wn, anh, 0, 0, 0);
        }

        // D layout: col = lane&15, row = (lane>>4)*4 + j
        #pragma unroll
        for (int j = 0; j < 4; ++j) {
            int row = kgrp * 4 + j;
            prz[wave * 512 + row * 32 + lrow]      = ar[j];
            prz[wave * 512 + row * 32 + 16 + lrow] = az[j];
            pnx[wave * 256 + row * 16 + lrow]      = anx[j];
            pnh[wave * 256 + row * 16 + lrow]      = anh[j];
        }
        __syncthreads();

        // ---- gate math: thread (mrow, jcol) owns one output element ----
        {
            float rpre = prz[mrow * 32 + jcol] + prz[512 + mrow * 32 + jcol]
                       + prz[1024 + mrow * 32 + jcol] + prz[1536 + mrow * 32 + jcol] + b_r;
            float zpre = prz[mrow * 32 + 16 + jcol] + prz[512 + mrow * 32 + 16 + jcol]
                       + prz[1024 + mrow * 32 + 16 + jcol] + prz[1536 + mrow * 32 + 16 + jcol] + b_z;
            float ginn = pnx[mrow * 16 + jcol] + pnx[256 + mrow * 16 + jcol]
                       + pnx[512 + mrow * 16 + jcol] + pnx[768 + mrow * 16 + jcol] + b_nx;
            float ghnn = pnh[mrow * 16 + jcol] + pnh[256 + mrow * 16 + jcol]
                       + pnh[512 + mrow * 16 + jcol] + pnh[768 + mrow * 16 + jcol] + b_nh;
            float r = sigmoid_f(rpre);
            float z = sigmoid_f(zpre);
            float n = tanh_f(ginn + r * ghnn);
            float hn = (1.0f - z) * n + z * hp;
            hp = hn;
            out[((size_t)(brow + mrow) * TT + t) * NH + hc0 + jcol] = hn;
            hbuf[(size_t)(p ^ 1) * NB * NH + (size_t)(brow + mrow) * NH + hc0 + jcol] = (__bf16)hn;
            if (t == TT - 1)
                out[(size_t)NB * TT * NH + (size_t)(brow + mrow) * NH + hc0 + jcol] = hn;
        }

        // ---- release: make h visible, then raise own flag ----
        if (t < TT - 1) {
            __threadfence();   // per-thread release (waitcnt + L2 writeback)
            __syncthreads();
            if (tid == 0)
                __hip_atomic_store(myflag, (unsigned)(t + 1), __ATOMIC_RELAXED,
                                   __HIP_MEMORY_SCOPE_AGENT);
        }
        p ^= 1;
    }
}

extern "C" void kernel_launch(void* const* d_in, const int* in_sizes, int n_in,
                              void* d_out, int out_size, void* d_ws, size_t ws_size,
                              hipStream_t stream) {
    (void)in_sizes; (void)n_in; (void)out_size;
    const float* x    = (const float*)d_in[0];
    const float* W_ih = (const float*)d_in[1];
    const float* W_hh = (const float*)d_in[2];
    const float* b_ih = (const float*)d_in[3];
    const float* b_hh = (const float*)d_in[4];
    float* out = (float*)d_out;

    // ws layout: [0,16K) flag lines (4 groups x 64 blocks x 64B);
    //            [16K, 16K+256K) bf16 h double buffer
    unsigned* flags = (unsigned*)d_ws;
    __bf16* hbuf = (__bf16*)((char*)d_ws + 16384);
    const size_t clear_bytes = 16384 + (size_t)NB * NH * sizeof(__bf16);  // flags + h[p=0]
    if (ws_size < 16384 + (size_t)2 * NB * NH * sizeof(__bf16)) return;
    hipMemsetAsync(d_ws, 0, clear_bytes, stream);  // replay-safe reset

    const size_t smem_bytes = 163840;
    (void)hipFuncSetAttribute((const void*)gru_kernel,
                              hipFuncAttributeMaxDynamicSharedMemorySize, (int)smem_bytes);
    gru_kernel<<<GRID, NTH, smem_bytes, stream>>>(x, W_ih, W_hh, b_ih, b_hh, out, flags, hbuf);
}

// Round 3
// 3685.672 us; speedup vs baseline: 7.8635x; 7.8635x over previous
//
#include <hip/hip_runtime.h>
#include <hip/hip_bf16.h>

#define NB 64
#define TT 1024
#define ND 512
#define NH 1024
#define GRID 256
#define NTH 256

typedef float f32x4 __attribute__((ext_vector_type(4)));
typedef __bf16 bf16x8 __attribute__((ext_vector_type(8)));

__device__ __forceinline__ float sigmoid_f(float v) { return 1.0f / (1.0f + __expf(-v)); }

__device__ __forceinline__ float tanh_f(float v) {
    float a = fabsf(v);
    float e = __expf(-2.0f * a);
    float t = (1.0f - e) / (1.0f + e);
    return copysignf(t, v);
}

// ---- device-scope (MALL-coherent, cache-bypassing) accessors: sc1 ----
// No __threadfence anywhere: sc1 stores are write-through to MALL (no dirty L2),
// sc1 loads read the MALL (no stale L1/L2) -> no wbl2/inv cache ops needed.
__device__ __forceinline__ f32x4 load_dwordx4_sc1(const void* p) {
    f32x4 r;
    asm volatile("global_load_dwordx4 %0, %1, off sc1" : "=v"(r) : "v"(p));
    return r;
}
__device__ __forceinline__ void store_short_sc1(void* p, unsigned v16) {
    asm volatile("global_store_short %0, %1, off sc1" :: "v"(p), "v"(v16) : "memory");
}
__device__ __forceinline__ void store_dword_sc1(unsigned* p, unsigned v) {
    asm volatile("global_store_dword %0, %1, off sc1" :: "v"(p), "v"(v) : "memory");
}
__device__ __forceinline__ unsigned load_dword_sc1_wait(const unsigned* p) {
    unsigned v;
    asm volatile("global_load_dword %0, %1, off sc1\n\ts_waitcnt vmcnt(0)"
                 : "=v"(v) : "v"(p) : "memory");
    return v;
}

// LDS weights in exact MFMA B-fragment order: every read is a lane-contiguous
// 1KB ds_read_b128 (conflict-free).
__global__ void __launch_bounds__(NTH) gru_kernel(
    const float* __restrict__ x, const float* __restrict__ W_ih,
    const float* __restrict__ W_hh, const float* __restrict__ b_ih,
    const float* __restrict__ b_hh, float* __restrict__ out,
    unsigned* __restrict__ flags, __bf16* __restrict__ hbuf)
{
    extern __shared__ char smem[];
    __bf16* WihF = (__bf16*)smem;                  // 4*4*3*64*8 bf16 = 49152 B
    __bf16* WhhF = WihF + 4 * 4 * 3 * 64 * 8;      // 4*8*3*64*8 bf16 = 98304 B
    float* prz = (float*)(WhhF + 4 * 8 * 3 * 64 * 8);  // [4][16][32] = 8192 B
    float* pnx = prz + 2048;                       // [4][16][16] = 4096 B
    float* pnh = pnx + 1024;                       // [4][16][16] = 4096 B
    // total 163840 B

    const int tid = threadIdx.x;
    const int bg = blockIdx.x >> 6;   // batch group (16 rows) — independent sync group
    const int cg = blockIdx.x & 63;   // hidden-col group (16 cols)
    const int brow = bg << 4;
    const int hc0 = cg << 4;

    // ---- one-time: fill fragment-ordered weight LDS (fp32 -> bf16) ----
    for (int s = tid; s < 4 * 4 * 3 * 64; s += NTH) {      // W_ih slots
        int lane = s & 63, r = s >> 6;
        int g = r % 3, r2 = r / 3;
        int it = r2 & 3, w = r2 >> 2;
        int k = w * 128 + it * 32 + (lane >> 4) * 8;
        int col = lane & 15;
        const float* src = W_ih + (size_t)(g * NH + hc0 + col) * ND + k;
        float4 va = *(const float4*)(src);
        float4 vb = *(const float4*)(src + 4);
        bf16x8 f;
        f[0] = (__bf16)va.x; f[1] = (__bf16)va.y; f[2] = (__bf16)va.z; f[3] = (__bf16)va.w;
        f[4] = (__bf16)vb.x; f[5] = (__bf16)vb.y; f[6] = (__bf16)vb.z; f[7] = (__bf16)vb.w;
        *(bf16x8*)(WihF + (size_t)s * 8) = f;
    }
    for (int s = tid; s < 4 * 8 * 3 * 64; s += NTH) {      // W_hh slots
        int lane = s & 63, r = s >> 6;
        int g = r % 3, r2 = r / 3;
        int it = r2 & 7, w = r2 >> 3;
        int k = w * 256 + it * 32 + (lane >> 4) * 8;
        int col = lane & 15;
        const float* src = W_hh + (size_t)(g * NH + hc0 + col) * NH + k;
        float4 va = *(const float4*)(src);
        float4 vb = *(const float4*)(src + 4);
        bf16x8 f;
        f[0] = (__bf16)va.x; f[1] = (__bf16)va.y; f[2] = (__bf16)va.z; f[3] = (__bf16)va.w;
        f[4] = (__bf16)vb.x; f[5] = (__bf16)vb.y; f[6] = (__bf16)vb.z; f[7] = (__bf16)vb.w;
        *(bf16x8*)(WhhF + (size_t)s * 8) = f;
    }

    const int jcol = tid & 15;
    const int mrow = tid >> 4;
    const float b_r = b_ih[hc0 + jcol] + b_hh[hc0 + jcol];
    const float b_z = b_ih[NH + hc0 + jcol] + b_hh[NH + hc0 + jcol];
    const float b_nx = b_ih[2 * NH + hc0 + jcol];
    const float b_nh = b_hh[2 * NH + hc0 + jcol];

    __syncthreads();

    const int wave = tid >> 6;
    const int lane = tid & 63;
    const int lrow = lane & 15;
    const int kgrp = lane >> 4;

    unsigned* myflag = flags + ((size_t)(bg * 64 + cg)) * 16;            // own 64B line
    const unsigned* pollflag = flags + ((size_t)(bg * 64 + (tid & 63))) * 16;

    // h-store address for gate-math role (per parity)
    __bf16* hst0 = hbuf + (size_t)NB * NH + (size_t)(brow + mrow) * NH + hc0 + jcol; // p^1 when p=0
    __bf16* hst1 = hbuf + (size_t)(brow + mrow) * NH + hc0 + jcol;                   // p^1 when p=1

    float hp = 0.0f;   // fp32 hidden-state carry in a register

    // prologue: prefetch x fragment for t=0
    f32x4 xa[4], xb[4];
    {
        const float* xr = x + ((size_t)(brow + lrow) * TT + 0) * ND + wave * 128 + kgrp * 8;
        #pragma unroll
        for (int it = 0; it < 4; ++it) {
            xa[it] = *(const f32x4*)(xr + it * 32);
            xb[it] = *(const f32x4*)(xr + it * 32 + 4);
        }
    }

    int p = 0;
    for (int t = 0; t < TT; ++t) {
        f32x4 ar{}, az{}, anx{}, anh{};

        // ---- x-part from prefetched registers (independent of peers) ----
        #pragma unroll
        for (int it = 0; it < 4; ++it) {
            bf16x8 af;
            af[0] = (__bf16)xa[it][0]; af[1] = (__bf16)xa[it][1];
            af[2] = (__bf16)xa[it][2]; af[3] = (__bf16)xa[it][3];
            af[4] = (__bf16)xb[it][0]; af[5] = (__bf16)xb[it][1];
            af[6] = (__bf16)xb[it][2]; af[7] = (__bf16)xb[it][3];
            const __bf16* wp = WihF + ((size_t)(wave * 4 + it) * 3) * 512 + lane * 8;
            bf16x8 wr = *(const bf16x8*)(wp);
            bf16x8 wz = *(const bf16x8*)(wp + 512);
            bf16x8 wn = *(const bf16x8*)(wp + 1024);
            ar  = __builtin_amdgcn_mfma_f32_16x16x32_bf16(af, wr, ar, 0, 0, 0);
            az  = __builtin_amdgcn_mfma_f32_16x16x32_bf16(af, wz, az, 0, 0, 0);
            anx = __builtin_amdgcn_mfma_f32_16x16x32_bf16(af, wn, anx, 0, 0, 0);
        }

        // ---- wait for peer h writes: poll 64 flag lines with sc1 loads ----
        if (t > 0) {
            if (tid < 64) {
                const unsigned tgt = (unsigned)t;
                for (;;) {
                    unsigned v = load_dword_sc1_wait(pollflag);
                    if (__all(v >= tgt)) break;
                }
            }
            __syncthreads();
        }

        // ---- h-part: issue all 8 sc1 loads, one wait, then MFMAs ----
        const __bf16* hrow = hbuf + (size_t)p * NB * NH + (size_t)(brow + lrow) * NH
                           + wave * 256 + kgrp * 8;
        f32x4 hraw[8];
        #pragma unroll
        for (int it = 0; it < 8; ++it)
            hraw[it] = load_dwordx4_sc1(hrow + it * 32);
        asm volatile("s_waitcnt vmcnt(0)" ::: "memory");
        __builtin_amdgcn_sched_barrier(0);
        #pragma unroll
        for (int it = 0; it < 8; ++it) {
            bf16x8 af = __builtin_bit_cast(bf16x8, hraw[it]);
            const __bf16* wp = WhhF + ((size_t)(wave * 8 + it) * 3) * 512 + lane * 8;
            bf16x8 wr = *(const bf16x8*)(wp);
            bf16x8 wz = *(const bf16x8*)(wp + 512);
            bf16x8 wn = *(const bf16x8*)(wp + 1024);
            ar  = __builtin_amdgcn_mfma_f32_16x16x32_bf16(af, wr, ar, 0, 0, 0);
            az  = __builtin_amdgcn_mfma_f32_16x16x32_bf16(af, wz, az, 0, 0, 0);
            anh = __builtin_amdgcn_mfma_f32_16x16x32_bf16(af, wn, anh, 0, 0, 0);
        }

        // ---- prefetch x(t+1) now; latency hides behind psum+gate+flag phase ----
        if (t + 1 < TT) {
            const float* xn = x + ((size_t)(brow + lrow) * TT + (t + 1)) * ND
                            + wave * 128 + kgrp * 8;
            #pragma unroll
            for (int it = 0; it < 4; ++it) {
                xa[it] = *(const f32x4*)(xn + it * 32);
                xb[it] = *(const f32x4*)(xn + it * 32 + 4);
            }
        }

        // D layout: col = lane&15, row = (lane>>4)*4 + j
        #pragma unroll
        for (int j = 0; j < 4; ++j) {
            int row = kgrp * 4 + j;
            prz[wave * 512 + row * 32 + lrow]      = ar[j];
            prz[wave * 512 + row * 32 + 16 + lrow] = az[j];
            pnx[wave * 256 + row * 16 + lrow]      = anx[j];
            pnh[wave * 256 + row * 16 + lrow]      = anh[j];
        }
        __syncthreads();

        // ---- gate math: thread (mrow, jcol) owns one output element ----
        {
            float rpre = prz[mrow * 32 + jcol] + prz[512 + mrow * 32 + jcol]
                       + prz[1024 + mrow * 32 + jcol] + prz[1536 + mrow * 32 + jcol] + b_r;
            float zpre = prz[mrow * 32 + 16 + jcol] + prz[512 + mrow * 32 + 16 + jcol]
                       + prz[1024 + mrow * 32 + 16 + jcol] + prz[1536 + mrow * 32 + 16 + jcol] + b_z;
            float ginn = pnx[mrow * 16 + jcol] + pnx[256 + mrow * 16 + jcol]
                       + pnx[512 + mrow * 16 + jcol] + pnx[768 + mrow * 16 + jcol] + b_nx;
            float ghnn = pnh[mrow * 16 + jcol] + pnh[256 + mrow * 16 + jcol]
                       + pnh[512 + mrow * 16 + jcol] + pnh[768 + mrow * 16 + jcol] + b_nh;
            float r = sigmoid_f(rpre);
            float z = sigmoid_f(zpre);
            float n = tanh_f(ginn + r * ghnn);
            float hn = (1.0f - z) * n + z * hp;
            hp = hn;
            out[((size_t)(brow + mrow) * TT + t) * NH + hc0 + jcol] = hn;   // plain cached store
            unsigned hb = (unsigned)__builtin_bit_cast(unsigned short, (__bf16)hn);
            store_short_sc1(p ? hst1 : hst0, hb);                           // write-through to MALL
            if (t == TT - 1)
                out[(size_t)NB * TT * NH + (size_t)(brow + mrow) * NH + hc0 + jcol] = hn;
        }

        // ---- release: drain own stores (ACK at MALL), block-sync, raise flag ----
        if (t < TT - 1) {
            asm volatile("s_waitcnt vmcnt(0)" ::: "memory");
            __syncthreads();
            if (tid == 0)
                store_dword_sc1(myflag, (unsigned)(t + 1));
        }
        p ^= 1;
    }
}

extern "C" void kernel_launch(void* const* d_in, const int* in_sizes, int n_in,
                              void* d_out, int out_size, void* d_ws, size_t ws_size,
                              hipStream_t stream) {
    (void)in_sizes; (void)n_in; (void)out_size;
    const float* x    = (const float*)d_in[0];
    const float* W_ih = (const float*)d_in[1];
    const float* W_hh = (const float*)d_in[2];
    const float* b_ih = (const float*)d_in[3];
    const float* b_hh = (const float*)d_in[4];
    float* out = (float*)d_out;

    // ws layout: [0,16K) flag lines (4 groups x 64 blocks x 64B);
    //            [16K, 16K+256K) bf16 h double buffer
    unsigned* flags = (unsigned*)d_ws;
    __bf16* hbuf = (__bf16*)((char*)d_ws + 16384);
    const size_t clear_bytes = 16384 + (size_t)NB * NH * sizeof(__bf16);  // flags + h[p=0]
    if (ws_size < 16384 + (size_t)2 * NB * NH * sizeof(__bf16)) return;
    hipMemsetAsync(d_ws, 0, clear_bytes, stream);  // replay-safe reset

    const size_t smem_bytes = 163840;
    (void)hipFuncSetAttribute((const void*)gru_kernel,
                              hipFuncAttributeMaxDynamicSharedMemorySize, (int)smem_bytes);
    gru_kernel<<<GRID, NTH, smem_bytes, stream>>>(x, W_ih, W_hh, b_ih, b_hh, out, flags, hbuf);
}